// Round 6
// baseline (21678.326 us; speedup 1.0000x reference)
//
#include <hip/hip_runtime.h>

// Problem dims
constexpr int kB    = 64;
constexpr int kT    = 512;
constexpr int kDin  = 256;
constexpr int kH    = 1024;
constexpr int kH3   = 3072;
constexpr int kDout = 256;
constexpr int kHB   = kB * kH;   // elements per h parity buffer

typedef float  f32x4  __attribute__((ext_vector_type(4)));
typedef __bf16 bf16x8 __attribute__((ext_vector_type(8)));
typedef unsigned long long u64;

__device__ __forceinline__ float b2f(unsigned short u) {
  union { float f; unsigned u32; } c; c.u32 = ((unsigned)u) << 16; return c.f;
}
__device__ __forceinline__ unsigned short f2b(float f) {
  union { float f; unsigned u32; } c; c.f = f;
  unsigned r = c.u32 + 0x7fffu + ((c.u32 >> 16) & 1u);  // RNE
  return (unsigned short)(r >> 16);
}
__device__ __forceinline__ bf16x8 ld8(const unsigned short* p) {
  return *reinterpret_cast<const bf16x8*>(p);
}
__device__ __forceinline__ u64 ald(const u64* p) {
  return __hip_atomic_load(p, __ATOMIC_RELAXED, __HIP_MEMORY_SCOPE_AGENT);
}
__device__ __forceinline__ unsigned ald32(const unsigned* p) {
  return __hip_atomic_load(p, __ATOMIC_RELAXED, __HIP_MEMORY_SCOPE_AGENT);
}
__device__ __forceinline__ void ast32(unsigned* p, unsigned v) {
  __hip_atomic_store(p, v, __ATOMIC_RELAXED, __HIP_MEMORY_SCOPE_AGENT);
}
__device__ __forceinline__ float sigm_(float x) { return 1.f / (1.f + __expf(-x)); }
__device__ __forceinline__ float tanh_(float x) {
  return 1.f - 2.f / (__expf(2.f * x) + 1.f);
}

#define MFMA16(a, b, c) __builtin_amdgcn_mfma_f32_16x16x32_bf16((a), (b), (c), 0, 0, 0)

// ---------------------------------------------------------------------------
// Prep: fp32->bf16 conversion, combined biases, zero h parity buffers + flags.
// ---------------------------------------------------------------------------
__global__ void gru_prep(const float* __restrict__ x,
                         const float* __restrict__ Wi0, const float* __restrict__ Wh0,
                         const float* __restrict__ bi0, const float* __restrict__ bh0,
                         const float* __restrict__ Wi1, const float* __restrict__ Wh1,
                         const float* __restrict__ bi1, const float* __restrict__ bh1,
                         unsigned short* __restrict__ xb,
                         unsigned short* __restrict__ wi0b, unsigned short* __restrict__ wh0b,
                         unsigned short* __restrict__ wi1b, unsigned short* __restrict__ wh1b,
                         unsigned short* __restrict__ h0, unsigned short* __restrict__ h1,
                         float* __restrict__ bias,
                         unsigned* __restrict__ flags0, unsigned* __restrict__ flags1) {
  const int stride = gridDim.x * blockDim.x;
  const int g = blockIdx.x * blockDim.x + threadIdx.x;
  for (int i = g; i < kH3 * kDin; i += stride) wi0b[i] = f2b(Wi0[i]);
  for (int i = g; i < kH3 * kH; i += stride) {
    wh0b[i] = f2b(Wh0[i]); wi1b[i] = f2b(Wi1[i]); wh1b[i] = f2b(Wh1[i]);
  }
  for (int i = g; i < kB * kT * kDin; i += stride) xb[i] = f2b(x[i]);
  for (int i = g; i < 2 * kHB; i += stride) { h0[i] = 0; h1[i] = 0; }
  for (int i = g; i < kH; i += stride) {
    bias[0 * kH + i] = bi0[0 * kH + i] + bh0[0 * kH + i];
    bias[1 * kH + i] = bi0[1 * kH + i] + bh0[1 * kH + i];
    bias[2 * kH + i] = bi0[2 * kH + i];
    bias[3 * kH + i] = bh0[2 * kH + i];
    bias[4 * kH + i] = bi1[0 * kH + i] + bh1[0 * kH + i];
    bias[5 * kH + i] = bi1[1 * kH + i] + bh1[1 * kH + i];
    bias[6 * kH + i] = bi1[2 * kH + i];
    bias[7 * kH + i] = bh1[2 * kH + i];
  }
  for (int i = g; i < 64; i += stride) { flags0[i] = 0; flags1[i] = 0; }
}

// ---------------------------------------------------------------------------
// Persistent GRU, 64 blocks x 1024 threads (16 waves). Block = (jt: 64 h-units,
// mt: 16 batch rows). Waves 0-7: layer0 tick t; waves 8-15: layer1 tick t-1.
// Flags (1 u32/producer/layer, monotonic tick counts) gate untagged bf16 h
// exchange; h republished through LDS so L0/L1 share one fabric read.
// ---------------------------------------------------------------------------
__global__ void __launch_bounds__(1024) gru_main(
    const unsigned short* __restrict__ xb,
    const unsigned short* __restrict__ wi0, const unsigned short* __restrict__ wh0,
    const unsigned short* __restrict__ wi1, const unsigned short* __restrict__ wh1,
    const float* __restrict__ bias,
    unsigned short* __restrict__ h0, unsigned short* __restrict__ h1,
    unsigned* __restrict__ flags0, unsigned* __restrict__ flags1,
    const float* __restrict__ Wo, const float* __restrict__ bo,
    float* __restrict__ out) {
  __shared__ unsigned short hl[2][16][1032];   // [layer-src][row][col(+8 pad)]
  __shared__ float red[2][4][4][64][5];        // [layer][js][gate][lane][reg+pad]

  const int tid   = threadIdx.x;
  const int lane  = tid & 63;
  const int wv    = tid >> 6;        // 0..15
  const int layer = wv >> 3;         // 0: L0, 1: L1
  const int sub   = wv & 7;          // 0..7 within layer
  const int kh    = sub >> 2;        // K half (512) for MFMA
  const int js    = sub & 3;         // j-subtile (16 units)

  // XCD swizzle: blockIdx%8 = XCD; XCD x hosts jt {2x,2x+1} x 4 mt (weight
  // slices L2-resident: ~2.6 MB/XCD).
  const int xcd  = blockIdx.x & 7;
  const int rest = blockIdx.x >> 3;
  const int mt   = rest & 3;
  const int jt   = xcd * 2 + (rest >> 2);   // 0..15
  const int jbase = jt * 64;

  const int ln15 = lane & 15;
  const int quad = lane >> 4;

  // B-frag weight row pointers (per wave): j-row jr, gate g at g*kH + jr.
  const int jr = jbase + js * 16 + ln15;
  const unsigned short* whb = (layer == 0) ? wh0 : wh1;
  const unsigned short* wh_r = whb + (size_t)(0 * kH + jr) * kH + kh * 512 + quad * 8;
  const unsigned short* wh_z = whb + (size_t)(1 * kH + jr) * kH + kh * 512 + quad * 8;
  const unsigned short* wh_n = whb + (size_t)(2 * kH + jr) * kH + kh * 512 + quad * 8;
  const unsigned short* wi_r, *wi_z, *wi_n;
  if (layer == 0) {
    wi_r = wi0 + (size_t)(0 * kH + jr) * kDin + kh * 128 + quad * 8;
    wi_z = wi0 + (size_t)(1 * kH + jr) * kDin + kh * 128 + quad * 8;
    wi_n = wi0 + (size_t)(2 * kH + jr) * kDin + kh * 128 + quad * 8;
  } else {
    wi_r = wi1 + (size_t)(0 * kH + jr) * kH + kh * 512 + quad * 8;
    wi_z = wi1 + (size_t)(1 * kH + jr) * kH + kh * 512 + quad * 8;
    wi_n = wi1 + (size_t)(2 * kH + jr) * kH + kh * 512 + quad * 8;
  }

  // Fabric-load slice for this wave: K-slice sub, 16 rows x 128 cols.
  const int gr = mt * 16 + ln15;             // global h row this lane loads
  const int c0 = sub * 128 + quad * 32;      // col base (32 bf16 = 8 u64)

  const int jgl = jbase + js * 16 + ln15;    // C/D col (global j)
  const float* bb = bias + layer * 4 * kH;
  const f32x4 z4 = {0.f, 0.f, 0.f, 0.f};

  for (int t = 0; t <= kT; ++t) {
    const int p0r = (t + 1) & 1, p0w = t & 1;        // h0: read t-1, write t
    const int p1r = t & 1,       p1w = (t + 1) & 1;  // h1: read t-2, write t-1
    const bool l0c = (t < kT);
    const bool l1c = (t >= 1);

    // ---------------- phase P+A: poll flags, fabric-load h, fill LDS -------
    bf16x8 xa[4];
    if (layer == 0) {
      if (l0c) {
        const unsigned short* xp =
            xb + (size_t)gr * (kT * kDin) + t * kDin + kh * 128 + quad * 8;
#pragma unroll
        for (int i = 0; i < 4; ++i) xa[i] = ld8(xp + i * 32);
      }
      // h0[t-1] ready <=> flags0[p] >= t  (flag v => wrote h0[v-1])
      for (;;) {
        int f = (lane < 16) ? (int)ald32(flags0 + mt * 16 + lane) : 0x7fffffff;
        if (__all(f >= t)) break;
        __builtin_amdgcn_s_sleep(2);
      }
      const u64* src = (const u64*)(h0 + (size_t)p0r * kHB + (size_t)gr * kH + c0);
      u64 w[8];
#pragma unroll
      for (int i = 0; i < 8; ++i) w[i] = ald(src + i);
#pragma unroll
      for (int i = 0; i < 8; ++i)
        *(u64*)&hl[0][ln15][c0 + i * 4] = w[i];
    } else {
      // h1[t-2] ready <=> flags1[p] >= t-1  (flag v => wrote h1[v-1])
      for (;;) {
        int f = (lane < 16) ? (int)ald32(flags1 + mt * 16 + lane) : 0x7fffffff;
        if (__all(f >= t - 1)) break;
        __builtin_amdgcn_s_sleep(2);
      }
      const u64* src = (const u64*)(h1 + (size_t)p1r * kHB + (size_t)gr * kH + c0);
      u64 w[8];
#pragma unroll
      for (int i = 0; i < 8; ++i) w[i] = ald(src + i);
#pragma unroll
      for (int i = 0; i < 8; ++i)
        *(u64*)&hl[1][ln15][c0 + i * 4] = w[i];
    }
    __syncthreads();  // B1: LDS h ready (also closes last tick's LDS reads)

    // ---------------- phase B: MFMA ----------------------------------------
    f32x4 ar = z4, az = z4, ai = z4, ah = z4;
    const bool active = (layer == 0) ? l0c : l1c;
    if (active) {
      if (layer == 0) {
#pragma unroll
        for (int ks = 0; ks < 16; ++ks) {
          bf16x8 a = *(const bf16x8*)&hl[0][ln15][kh * 512 + ks * 32 + quad * 8];
          ar = MFMA16(a, ld8(wh_r + ks * 32), ar);
          az = MFMA16(a, ld8(wh_z + ks * 32), az);
          ah = MFMA16(a, ld8(wh_n + ks * 32), ah);
        }
#pragma unroll
        for (int ks = 0; ks < 4; ++ks) {
          ar = MFMA16(xa[ks], ld8(wi_r + ks * 32), ar);
          az = MFMA16(xa[ks], ld8(wi_z + ks * 32), az);
          ai = MFMA16(xa[ks], ld8(wi_n + ks * 32), ai);
        }
      } else {
#pragma unroll
        for (int ks = 0; ks < 16; ++ks) {
          bf16x8 a0 = *(const bf16x8*)&hl[0][ln15][kh * 512 + ks * 32 + quad * 8];
          ar = MFMA16(a0, ld8(wi_r + ks * 32), ar);
          az = MFMA16(a0, ld8(wi_z + ks * 32), az);
          ai = MFMA16(a0, ld8(wi_n + ks * 32), ai);
          bf16x8 a1 = *(const bf16x8*)&hl[1][ln15][kh * 512 + ks * 32 + quad * 8];
          ar = MFMA16(a1, ld8(wh_r + ks * 32), ar);
          az = MFMA16(a1, ld8(wh_z + ks * 32), az);
          ah = MFMA16(a1, ld8(wh_n + ks * 32), ah);
        }
      }
    }

    // ---------------- phase C: K-reduce (2-way) + gates + store ------------
    if (kh == 1) {
#pragma unroll
      for (int q = 0; q < 4; ++q) {
        red[layer][js][0][lane][q] = ar[q]; red[layer][js][1][lane][q] = az[q];
        red[layer][js][2][lane][q] = ai[q]; red[layer][js][3][lane][q] = ah[q];
      }
    }
    __syncthreads();  // B2

    if (active && kh == 0) {
      float hv4[4];
#pragma unroll
      for (int q = 0; q < 4; ++q) {
        float sr = ar[q] + red[layer][js][0][lane][q];
        float sz = az[q] + red[layer][js][1][lane][q];
        float si = ai[q] + red[layer][js][2][lane][q];
        float sh = ah[q] + red[layer][js][3][lane][q];
        float rg = sigm_(sr + bb[jgl]);
        float zg = sigm_(sz + bb[kH + jgl]);
        float ng = tanh_(si + bb[2 * kH + jgl] + rg * (sh + bb[3 * kH + jgl]));
        // BUGFIX (round 5): previous h column is the GLOBAL j (jbase + ...),
        // not the block-local js*16+ln15 — hl rows span all 1024 h columns.
        float hp = b2f(hl[layer][quad * 4 + q][jbase + js * 16 + ln15]);
        hv4[q] = (1.f - zg) * ng + zg * hp;
      }
      unsigned short* dst = (layer == 0) ? h0 + (size_t)p0w * kHB
                                         : h1 + (size_t)p1w * kHB;
#pragma unroll
      for (int q = 0; q < 4; ++q) {
        float pv = __shfl_xor(hv4[q], 1);
        if (!(lane & 1)) {
          unsigned pk = (unsigned)f2b(hv4[q]) | ((unsigned)f2b(pv) << 16);
          unsigned* d = (unsigned*)(dst + (size_t)(mt * 16 + quad * 4 + q) * kH +
                                    jbase + js * 16 + (ln15 & ~1));
          ast32(d, pk);
        }
      }
    }
    __syncthreads();  // B3: drains h stores (vmcnt) before flag publish

    if (tid == 0 && l0c) ast32(flags0 + mt * 16 + jt, (unsigned)(t + 1));
    if (tid == 512 && l1c) ast32(flags1 + mt * 16 + jt, (unsigned)t);
  }

  // ---------------- output projection: out = h1[511] @ Wo^T + bo -----------
  // h1[511] lives in parity 1 (written at t=512), flag1 = 512.
  for (;;) {
    int f = (wv == 0 && lane < 16) ? (int)ald32(flags1 + mt * 16 + lane)
                                   : 0x7fffffff;
    if (__all(f >= (int)kT)) break;
    __builtin_amdgcn_s_sleep(2);
  }
  __syncthreads();
  {  // stage h1[511] rows (mt*16..+16, all 1024) into hl[0]
    const u64* src = (const u64*)(h1 + (size_t)1 * kHB +
                                  (size_t)(mt * 16 + wv) * kH + lane * 16);
    u64 w[4];
#pragma unroll
    for (int i = 0; i < 4; ++i) w[i] = ald(src + i);
#pragma unroll
    for (int i = 0; i < 4; ++i)
      *(u64*)&hl[0][wv][lane * 16 + i * 4] = w[i];
  }
  __syncthreads();
  if (tid < 256) {
    const int r  = tid >> 4;           // 0..15 batch row within mt
    const int oc = tid & 15;           // 0..15 out col within jt
    const int o  = jt * 16 + oc;
    const float* wrow = Wo + (size_t)o * kH;
    const unsigned short* hs = &hl[0][r][0];
    float acc = bo[o];
#pragma unroll 8
    for (int k = 0; k < kH; k += 4) {
      float4 w4 = *reinterpret_cast<const float4*>(wrow + k);
      acc += b2f(hs[k + 0]) * w4.x + b2f(hs[k + 1]) * w4.y +
             b2f(hs[k + 2]) * w4.z + b2f(hs[k + 3]) * w4.w;
    }
    out[(mt * 16 + r) * kDout + o] = acc;
  }
}

// ---------------------------------------------------------------------------
extern "C" void kernel_launch(void* const* d_in, const int* in_sizes, int n_in,
                              void* d_out, int out_size, void* d_ws, size_t ws_size,
                              hipStream_t stream) {
  const float* x   = (const float*)d_in[0];
  const float* Wi0 = (const float*)d_in[1];
  const float* Wh0 = (const float*)d_in[2];
  const float* bi0 = (const float*)d_in[3];
  const float* bh0 = (const float*)d_in[4];
  const float* Wi1 = (const float*)d_in[5];
  const float* Wh1 = (const float*)d_in[6];
  const float* bi1 = (const float*)d_in[7];
  const float* bh1 = (const float*)d_in[8];
  const float* Wo  = (const float*)d_in[9];
  const float* bo  = (const float*)d_in[10];

  char* ws = (char*)d_ws;
  size_t off = 0;
  auto take = [&](size_t bytes) {
    size_t r = off;
    off += (bytes + 255) & ~(size_t)255;
    return r;
  };
  unsigned short* xb   = (unsigned short*)(ws + take((size_t)kB * kT * kDin * 2));
  unsigned short* wi0b = (unsigned short*)(ws + take((size_t)kH3 * kDin * 2));
  unsigned short* wh0b = (unsigned short*)(ws + take((size_t)kH3 * kH * 2));
  unsigned short* wi1b = (unsigned short*)(ws + take((size_t)kH3 * kH * 2));
  unsigned short* wh1b = (unsigned short*)(ws + take((size_t)kH3 * kH * 2));
  unsigned short* h0   = (unsigned short*)(ws + take((size_t)2 * kHB * 2));
  unsigned short* h1   = (unsigned short*)(ws + take((size_t)2 * kHB * 2));
  float*          bias = (float*)(ws + take(8 * kH * sizeof(float)));
  unsigned*       flags0 = (unsigned*)(ws + take(64 * 4));
  unsigned*       flags1 = (unsigned*)(ws + take(64 * 4));

  gru_prep<<<2048, 256, 0, stream>>>(x, Wi0, Wh0, bi0, bh0, Wi1, Wh1, bi1, bh1,
                                     xb, wi0b, wh0b, wi1b, wh1b, h0, h1, bias,
                                     flags0, flags1);
  gru_main<<<64, 1024, 0, stream>>>(xb, wi0b, wh0b, wi1b, wh1b, bias, h0, h1,
                                    flags0, flags1, Wo, bo, (float*)d_out);
}

// Round 8
// 7381.083 us; speedup vs baseline: 2.9370x; 2.9370x over previous
//
#include <hip/hip_runtime.h>

// Problem dims
constexpr int kB    = 64;
constexpr int kT    = 512;
constexpr int kDin  = 256;
constexpr int kH    = 1024;
constexpr int kH3   = 3072;
constexpr int kDout = 256;
constexpr int kHB   = kB * kH;   // elements per ring slot (128 KB)

typedef float  f32x4  __attribute__((ext_vector_type(4)));
typedef __bf16 bf16x8 __attribute__((ext_vector_type(8)));
typedef unsigned u32x4 __attribute__((ext_vector_type(4)));
typedef unsigned long long u64;

__device__ __forceinline__ float b2f(unsigned short u) {
  union { float f; unsigned u32; } c; c.u32 = ((unsigned)u) << 16; return c.f;
}
__device__ __forceinline__ unsigned short f2b(float f) {
  union { float f; unsigned u32; } c; c.f = f;
  unsigned r = c.u32 + 0x7fffu + ((c.u32 >> 16) & 1u);  // RNE
  return (unsigned short)(r >> 16);
}
__device__ __forceinline__ bf16x8 ld8(const unsigned short* p) {
  return *reinterpret_cast<const bf16x8*>(p);
}
__device__ __forceinline__ u64 ald(const u64* p) {
  return __hip_atomic_load(p, __ATOMIC_RELAXED, __HIP_MEMORY_SCOPE_AGENT);
}
__device__ __forceinline__ unsigned ald32(const unsigned* p) {
  return __hip_atomic_load(p, __ATOMIC_RELAXED, __HIP_MEMORY_SCOPE_AGENT);
}
__device__ __forceinline__ void ast32(unsigned* p, unsigned v) {
  __hip_atomic_store(p, v, __ATOMIC_RELAXED, __HIP_MEMORY_SCOPE_AGENT);
}
__device__ __forceinline__ float sigm_(float x) { return 1.f / (1.f + __expf(-x)); }
__device__ __forceinline__ float tanh_(float x) {
  return 1.f - 2.f / (__expf(2.f * x) + 1.f);
}

#define MFMA16(a, b, c) __builtin_amdgcn_mfma_f32_16x16x32_bf16((a), (b), (c), 0, 0, 0)

// sync[]: [0..255] fl0[mtile][64]; [256..511] fl1[mtile][64]
// ---------------------------------------------------------------------------
__global__ void gru_prep(const float* __restrict__ x,
                         const float* __restrict__ Wi0, const float* __restrict__ Wh0,
                         const float* __restrict__ bi0, const float* __restrict__ bh0,
                         const float* __restrict__ Wi1, const float* __restrict__ Wh1,
                         const float* __restrict__ bi1, const float* __restrict__ bh1,
                         unsigned short* __restrict__ xb,
                         unsigned short* __restrict__ wi0b, unsigned short* __restrict__ wh0b,
                         unsigned short* __restrict__ wi1b, unsigned short* __restrict__ wh1b,
                         unsigned short* __restrict__ r0, unsigned short* __restrict__ r1,
                         float* __restrict__ bias, unsigned* __restrict__ sync) {
  const int stride = gridDim.x * blockDim.x;
  const int g = blockIdx.x * blockDim.x + threadIdx.x;
  for (int i = g; i < kH3 * kDin; i += stride) wi0b[i] = f2b(Wi0[i]);
  for (int i = g; i < kH3 * kH; i += stride) {
    wh0b[i] = f2b(Wh0[i]); wi1b[i] = f2b(Wi1[i]); wh1b[i] = f2b(Wh1[i]);
  }
  for (int i = g; i < kB * kT * kDin; i += stride) xb[i] = f2b(x[i]);
  for (int i = g; i < kHB; i += stride) { r0[i] = 0; r1[i] = 0; }  // slot 0 = h[-1]
  for (int i = g; i < kH; i += stride) {
    bias[0 * kH + i] = bi0[0 * kH + i] + bh0[0 * kH + i];
    bias[1 * kH + i] = bi0[1 * kH + i] + bh0[1 * kH + i];
    bias[2 * kH + i] = bi0[2 * kH + i];
    bias[3 * kH + i] = bh0[2 * kH + i];
    bias[4 * kH + i] = bi1[0 * kH + i] + bh1[0 * kH + i];
    bias[5 * kH + i] = bi1[1 * kH + i] + bh1[1 * kH + i];
    bias[6 * kH + i] = bi1[2 * kH + i];
    bias[7 * kH + i] = bh1[2 * kH + i];
  }
  for (int i = g; i < 1024; i += stride) sync[i] = 0;
}

// ---------------------------------------------------------------------------
// Persistent GRU. 256 blocks x 256 thr (4 waves, 1 blk/CU, 1 wave/SIMD).
// Block = (xcd=blockIdx&7, jsub, mtile): 16 j-units x 16 batch rows; waves
// 0-1: L0@t (K-split-2), waves 2-3: L1@t-1. h exchange through a
// tick-indexed ring: producers store sc1 (coherent point), consumers read
// with PLAIN CACHED loads (addresses never reused within a launch -> no
// staleness; per-XCD L2 fans a slot out to its 32 blocks). rmode==0 falls
// back to parity-2 + sc1 atomic reads (R6-proven protocol).
// Flags: fl0/fl1 per (mtile, producer), monotonic; wave 0 polls, throttled.
// ---------------------------------------------------------------------------
__global__ void __launch_bounds__(256, 1) gru_main(
    const unsigned short* __restrict__ xb,
    const unsigned short* __restrict__ wi0, const unsigned short* __restrict__ wh0,
    const unsigned short* __restrict__ wi1, const unsigned short* __restrict__ wh1,
    const float* __restrict__ bias,
    unsigned short* __restrict__ r0, unsigned short* __restrict__ r1,
    unsigned* __restrict__ sync, const int rmode,
    const float* __restrict__ Wo, const float* __restrict__ bo,
    float* __restrict__ out) {
  __shared__ unsigned short hl0[16][1032];   // h0[t-1] rows of mtile, full K
  __shared__ unsigned short hl1[16][1032];   // h1[t-2] rows of mtile, full K
  __shared__ float red[2][4][64][5];         // [layer][gate][lane][reg(+pad)]

  const int tid  = threadIdx.x;
  const int lane = tid & 63;
  const int wv   = tid >> 6;        // 0..3
  const int ln15 = lane & 15;
  const int quad = lane >> 4;

  const int xcd   = blockIdx.x & 7;      // L2-locality heuristic only
  const int rest  = blockIdx.x >> 3;
  const int jsub  = rest & 7;
  const int mtile = rest >> 3;           // 0..3
  const int pidx  = xcd * 8 + jsub;      // producer index 0..63

  const int layer = wv >> 1;             // waves 0,1 -> L0; 2,3 -> L1
  const int kh    = wv & 1;              // K-half
  const int jrow  = xcd * 128 + jsub * 16 + ln15;
  const int jcol  = jrow;

  const unsigned short *pw_r, *pw_z, *pw_n, *pv_r, *pv_z, *pv_n;
  if (layer == 0) {
    pw_r = wh0 + (size_t)(0 * kH + jrow) * kH + kh * 512 + quad * 8;
    pw_z = wh0 + (size_t)(1 * kH + jrow) * kH + kh * 512 + quad * 8;
    pw_n = wh0 + (size_t)(2 * kH + jrow) * kH + kh * 512 + quad * 8;
    pv_r = wi0 + (size_t)(0 * kH + jrow) * kDin + kh * 128 + quad * 8;
    pv_z = wi0 + (size_t)(1 * kH + jrow) * kDin + kh * 128 + quad * 8;
    pv_n = wi0 + (size_t)(2 * kH + jrow) * kDin + kh * 128 + quad * 8;
  } else {
    pw_r = wh1 + (size_t)(0 * kH + jrow) * kH + kh * 512 + quad * 8;
    pw_z = wh1 + (size_t)(1 * kH + jrow) * kH + kh * 512 + quad * 8;
    pw_n = wh1 + (size_t)(2 * kH + jrow) * kH + kh * 512 + quad * 8;
    pv_r = wi1 + (size_t)(0 * kH + jrow) * kH + kh * 512 + quad * 8;
    pv_z = wi1 + (size_t)(1 * kH + jrow) * kH + kh * 512 + quad * 8;
    pv_n = wi1 + (size_t)(2 * kH + jrow) * kH + kh * 512 + quad * 8;
  }

  const float* bb = bias + layer * 4 * kH;
  const f32x4 z4 = {0.f, 0.f, 0.f, 0.f};
  unsigned* fl0 = sync + mtile * 64;
  unsigned* fl1 = sync + 256 + mtile * 64;

  for (int t = 0; t <= kT; ++t) {
    const bool l0c = (t < kT);
    const bool l1c = (t >= 1);
    // ring slots (rmode=1: tick index; rmode=0: parity)
    const int s0r = rmode ? t : (t & 1);
    const int s0w = rmode ? (t + 1) : ((t + 1) & 1);
    const int s1r = rmode ? (t >= 1 ? t - 1 : 0) : ((t >= 1 ? t - 1 : 0) & 1);
    const int s1w = rmode ? t : (t & 1);

    // x fragment prefetch (plain cached; overlaps the poll)
    bf16x8 xa[4];
    if (layer == 0 && l0c) {
      const unsigned short* xp = xb + (size_t)(mtile * 16 + ln15) * (kT * kDin) +
                                 t * kDin + kh * 128 + quad * 8;
#pragma unroll
      for (int i = 0; i < 4; ++i) xa[i] = ld8(xp + i * 32);
    }

    // ---- wave 0 polls (throttled); others park at B0 ----------------------
    if (wv == 0) {
      for (;;) {
        int a = (int)ald32(fl0 + lane);
        int b = (int)ald32(fl1 + lane);
        if (__all(a >= t && b >= t - 1)) break;
        __builtin_amdgcn_s_sleep(32);
      }
    }
    __syncthreads();  // B0: h[t-1]/h[t-2] globally ready (+ parity WAR safe)

    // ---- stage h rows of mtile into LDS -----------------------------------
    {
      const int r = tid >> 4, s = tid & 15;   // row 0..15, 128B segment 0..15
      const unsigned short* b0 =
          r0 + (size_t)s0r * kHB + (size_t)(mtile * 16 + r) * kH + s * 64;
      const unsigned short* b1 =
          r1 + (size_t)s1r * kHB + (size_t)(mtile * 16 + r) * kH + s * 64;
      if (rmode) {
        u32x4 d0[8], d1[8];
#pragma unroll
        for (int i = 0; i < 8; ++i) d0[i] = *(const u32x4*)(b0 + i * 8);
#pragma unroll
        for (int i = 0; i < 8; ++i) d1[i] = *(const u32x4*)(b1 + i * 8);
#pragma unroll
        for (int i = 0; i < 8; ++i) *(u32x4*)&hl0[r][s * 64 + i * 8] = d0[i];
#pragma unroll
        for (int i = 0; i < 8; ++i) *(u32x4*)&hl1[r][s * 64 + i * 8] = d1[i];
      } else {
        u64 w0[16], w1[16];
#pragma unroll
        for (int i = 0; i < 16; ++i) w0[i] = ald((const u64*)b0 + i);
#pragma unroll
        for (int i = 0; i < 16; ++i) w1[i] = ald((const u64*)b1 + i);
#pragma unroll
        for (int i = 0; i < 16; ++i) *(u64*)&hl0[r][s * 64 + i * 4] = w0[i];
#pragma unroll
        for (int i = 0; i < 16; ++i) *(u64*)&hl1[r][s * 64 + i * 4] = w1[i];
      }
    }
    __syncthreads();  // B1: LDS staged

    // ---- MFMA -------------------------------------------------------------
    f32x4 a_r = z4, a_z = z4, a_i = z4, a_h = z4;
    const bool active = (layer == 0) ? l0c : l1c;
    if (active) {
      const int kb = kh * 512;
      if (layer == 0) {
#pragma unroll
        for (int kk = 0; kk < 16; ++kk) {
          bf16x8 A = *(const bf16x8*)&hl0[ln15][kb + kk * 32 + quad * 8];
          a_r = MFMA16(A, ld8(pw_r + kk * 32), a_r);
          a_z = MFMA16(A, ld8(pw_z + kk * 32), a_z);
          a_h = MFMA16(A, ld8(pw_n + kk * 32), a_h);
        }
#pragma unroll
        for (int kk = 0; kk < 4; ++kk) {
          a_r = MFMA16(xa[kk], ld8(pv_r + kk * 32), a_r);
          a_z = MFMA16(xa[kk], ld8(pv_z + kk * 32), a_z);
          a_i = MFMA16(xa[kk], ld8(pv_n + kk * 32), a_i);
        }
      } else {
#pragma unroll
        for (int kk = 0; kk < 16; ++kk) {
          bf16x8 A0 = *(const bf16x8*)&hl0[ln15][kb + kk * 32 + quad * 8];
          a_r = MFMA16(A0, ld8(pv_r + kk * 32), a_r);
          a_z = MFMA16(A0, ld8(pv_z + kk * 32), a_z);
          a_i = MFMA16(A0, ld8(pv_n + kk * 32), a_i);
          bf16x8 A1 = *(const bf16x8*)&hl1[ln15][kb + kk * 32 + quad * 8];
          a_r = MFMA16(A1, ld8(pw_r + kk * 32), a_r);
          a_z = MFMA16(A1, ld8(pw_z + kk * 32), a_z);
          a_h = MFMA16(A1, ld8(pw_n + kk * 32), a_h);
        }
      }
    }

    // ---- 2-way K-reduce + gates + sc1 h store -----------------------------
    if (((wv == 1) && l0c) || ((wv == 3) && l1c)) {
#pragma unroll
      for (int q = 0; q < 4; ++q) {
        red[layer][0][lane][q] = a_r[q]; red[layer][1][lane][q] = a_z[q];
        red[layer][2][lane][q] = a_i[q]; red[layer][3][lane][q] = a_h[q];
      }
    }
    __syncthreads();  // B2

    if (((wv == 0) && l0c) || ((wv == 2) && l1c)) {
      float hv4[4];
#pragma unroll
      for (int q = 0; q < 4; ++q) {
        float sr = a_r[q] + red[layer][0][lane][q];
        float sz = a_z[q] + red[layer][1][lane][q];
        float si = a_i[q] + red[layer][2][lane][q];
        float sh = a_h[q] + red[layer][3][lane][q];
        float rg = sigm_(sr + bb[jcol]);
        float zg = sigm_(sz + bb[kH + jcol]);
        float ng = tanh_(si + bb[2 * kH + jcol] + rg * (sh + bb[3 * kH + jcol]));
        float hp = (layer == 0) ? b2f(hl0[quad * 4 + q][jcol])
                                : b2f(hl1[quad * 4 + q][jcol]);
        hv4[q] = (1.f - zg) * ng + zg * hp;
      }
      unsigned short* dst = (layer == 0) ? r0 + (size_t)s0w * kHB
                                         : r1 + (size_t)s1w * kHB;
#pragma unroll
      for (int q = 0; q < 4; ++q) {
        float pv = __shfl_xor(hv4[q], 1);
        if (!(lane & 1)) {
          unsigned pk = (unsigned)f2b(hv4[q]) | ((unsigned)f2b(pv) << 16);
          unsigned* d = (unsigned*)(dst + (size_t)(mtile * 16 + quad * 4 + q) * kH +
                                    (jcol & ~1));
          ast32(d, pk);
        }
      }
    }
    __syncthreads();  // B3: drains h sc1 stores (vmcnt) before flag publish

    if (tid == 0 && l0c) ast32(&fl0[pidx], (unsigned)(t + 1));
    if (tid == 128 && l1c) ast32(&fl1[pidx], (unsigned)t);
  }

  // ---------------- output projection: out = h1[511] @ Wo^T + bo -----------
  if (wv == 0) {
    for (;;) {
      int f = (int)ald32(fl1 + lane);
      if (__all(f >= (int)kT)) break;
      __builtin_amdgcn_s_sleep(32);
    }
  }
  __syncthreads();
  {
    const int sfin = rmode ? kT : 0;   // slot holding h1[511]
    const int r = tid >> 4, s = tid & 15;
    const unsigned short* b1 =
        r1 + (size_t)sfin * kHB + (size_t)(mtile * 16 + r) * kH + s * 64;
    if (rmode) {
      u32x4 d[8];
#pragma unroll
      for (int i = 0; i < 8; ++i) d[i] = *(const u32x4*)(b1 + i * 8);
#pragma unroll
      for (int i = 0; i < 8; ++i) *(u32x4*)&hl0[r][s * 64 + i * 8] = d[i];
    } else {
      u64 w[16];
#pragma unroll
      for (int i = 0; i < 16; ++i) w[i] = ald((const u64*)b1 + i);
#pragma unroll
      for (int i = 0; i < 16; ++i) *(u64*)&hl0[r][s * 64 + i * 4] = w[i];
    }
  }
  __syncthreads();
  {
    const int c  = tid & 31;          // 32 out cols per jsub
    const int rr = tid >> 5;          // rows rr and rr+8
    const int col = jsub * 32 + c;
    const float* wr = Wo + (size_t)col * kH;
    float acc0 = bo[col], acc1 = bo[col];
#pragma unroll 8
    for (int k = 0; k < kH; k += 4) {
      float4 w4 = *reinterpret_cast<const float4*>(wr + k);
      acc0 += b2f(hl0[rr][k]) * w4.x + b2f(hl0[rr][k + 1]) * w4.y +
              b2f(hl0[rr][k + 2]) * w4.z + b2f(hl0[rr][k + 3]) * w4.w;
      acc1 += b2f(hl0[rr + 8][k]) * w4.x + b2f(hl0[rr + 8][k + 1]) * w4.y +
              b2f(hl0[rr + 8][k + 2]) * w4.z + b2f(hl0[rr + 8][k + 3]) * w4.w;
    }
    out[(mtile * 16 + rr) * kDout + col] = acc0;
    out[(mtile * 16 + rr + 8) * kDout + col] = acc1;
  }
}

// ---------------------------------------------------------------------------
extern "C" void kernel_launch(void* const* d_in, const int* in_sizes, int n_in,
                              void* d_out, int out_size, void* d_ws, size_t ws_size,
                              hipStream_t stream) {
  const float* x   = (const float*)d_in[0];
  const float* Wi0 = (const float*)d_in[1];
  const float* Wh0 = (const float*)d_in[2];
  const float* bi0 = (const float*)d_in[3];
  const float* bh0 = (const float*)d_in[4];
  const float* Wi1 = (const float*)d_in[5];
  const float* Wh1 = (const float*)d_in[6];
  const float* bi1 = (const float*)d_in[7];
  const float* bh1 = (const float*)d_in[8];
  const float* Wo  = (const float*)d_in[9];
  const float* bo  = (const float*)d_in[10];

  char* ws = (char*)d_ws;
  size_t off = 0;
  auto take = [&](size_t bytes) {
    size_t r = off;
    off += (bytes + 255) & ~(size_t)255;
    return r;
  };
  unsigned short* xb   = (unsigned short*)(ws + take((size_t)kB * kT * kDin * 2));
  unsigned short* wi0b = (unsigned short*)(ws + take((size_t)kH3 * kDin * 2));
  unsigned short* wh0b = (unsigned short*)(ws + take((size_t)kH3 * kH * 2));
  unsigned short* wi1b = (unsigned short*)(ws + take((size_t)kH3 * kH * 2));
  unsigned short* wh1b = (unsigned short*)(ws + take((size_t)kH3 * kH * 2));
  float*          bias = (float*)(ws + take(8 * kH * sizeof(float)));
  unsigned*       sync = (unsigned*)(ws + take(1024 * sizeof(unsigned)));

  // Ring: 513 slots of 128 KB per layer if workspace allows, else parity-2.
  const size_t slot_b = (size_t)kHB * 2;
  int rmode = 1;
  size_t ring_slots = (size_t)kT + 1;
  if (off + 2 * (ring_slots * slot_b) + (1u << 20) > ws_size) {
    rmode = 0;
    ring_slots = 2;
  }
  unsigned short* r0 = (unsigned short*)(ws + take(ring_slots * slot_b));
  unsigned short* r1 = (unsigned short*)(ws + take(ring_slots * slot_b));

  gru_prep<<<2048, 256, 0, stream>>>(x, Wi0, Wh0, bi0, bh0, Wi1, Wh1, bi1, bh1,
                                     xb, wi0b, wh0b, wi1b, wh1b, r0, r1, bias,
                                     sync);
  gru_main<<<256, 256, 0, stream>>>(xb, wi0b, wh0b, wi1b, wh1b, bias, r0, r1,
                                    sync, rmode, Wo, bo, (float*)d_out);
}